// Round 5
// baseline (438.751 us; speedup 1.0000x reference)
//
#include <hip/hip_runtime.h>
#include <math.h>

#define BSZ    256
#define GRID_N 49
#define LSTMH  512
#define CNN_C  2048
#define PROJ   512
#define KAUG   2560               // [cnn k=0..2047 | lstm k=2048..2559]
#define M_TOT  12544              // 256*49 = 196*64 exactly
#define MT     64
#define NT     256
#define BK     128
#define KTILES (KAUG / BK)        // 20
#define NBLK   ((M_TOT / MT) * (PROJ / NT))   // 392

typedef short bf16x8 __attribute__((ext_vector_type(8)));
typedef float f32x4  __attribute__((ext_vector_type(4)));

static __device__ __forceinline__ unsigned short bf16_rne(float f) {
    unsigned int u = __float_as_uint(f);
    u = u + 0x7FFFu + ((u >> 16) & 1u);
    return (unsigned short)(u >> 16);
}
static __device__ __forceinline__ uint4 pack8f(const float* f) {
    uint4 o;
    o.x = (unsigned int)bf16_rne(f[0]) | ((unsigned int)bf16_rne(f[1]) << 16);
    o.y = (unsigned int)bf16_rne(f[2]) | ((unsigned int)bf16_rne(f[3]) << 16);
    o.z = (unsigned int)bf16_rne(f[4]) | ((unsigned int)bf16_rne(f[5]) << 16);
    o.w = (unsigned int)bf16_rne(f[6]) | ((unsigned int)bf16_rne(f[7]) << 16);
    return o;
}
static __device__ __forceinline__ float tanh_fast(float x) {
    float e = __expf(2.f * x);
    return 1.f - 2.f / (e + 1.f);
}

// ---- Prep: W_aug (512 x 2560) fp32 -> bf16(RNE) into d_ws (proven r2/r3) ----
__global__ __launch_bounds__(256) void prep_w(const float* __restrict__ Wc,
                                              const float* __restrict__ Wl,
                                              unsigned short* __restrict__ wsW) {
    int c  = blockIdx.x * 256 + threadIdx.x;   // 512*320 chunks exactly
    int p  = c / 320;
    int kc = (c % 320) * 8;
    const float* src = (kc < CNN_C) ? (Wc + (size_t)p * CNN_C + kc)
                                    : (Wl + (size_t)p * LSTMH + (kc - CNN_C));
    float f[8];
    *(float4*)&f[0] = ((const float4*)src)[0];
    *(float4*)&f[4] = ((const float4*)src)[1];
    *(uint4*)(wsW + (size_t)p * KAUG + kc) = pack8f(f);
}

// ---- Main GEMM: 64x256 tile, BK=128, 20 K-tiles. Single-buffer LDS (80 KB),
// all staging via global->VGPR->ds_write (no glds => barriers wait lgkm only).
// Loads for tile kt+1 issued at top of iter kt (latency hidden by compute).
template <bool WS>
__global__ __launch_bounds__(256, 2) void gemm_k(
    const float* __restrict__ lstm, const float* __restrict__ cnn,
    const float* __restrict__ Wc,   const float* __restrict__ Wl,
    const float* __restrict__ bl,   const float* __restrict__ bc,
    const float* __restrict__ wat,  const unsigned short* __restrict__ wsW,
    float* __restrict__ out)
{
    __shared__ unsigned short Ash[MT][BK];   // 16 KB (zp aliased here in epilogue)
    __shared__ unsigned short Bsh[NT][BK];   // 64 KB

    const int t   = threadIdx.x;
    const int w   = t >> 6;
    const int l   = t & 63;
    const int q   = l >> 4;
    const int r16 = l & 15;

    const int m0 = (int)(blockIdx.x >> 1) * MT;
    const int n0 = (int)(blockIdx.x & 1) * NT;

    // A staging: thread t owns row ra, logical chunks seg*4..seg*4+3 (fp32 128B contig)
    const int ra  = t >> 2;
    const int seg = t & 3;
    const int swa = ra & 15;
    const int grow = m0 + ra;
    const int ab   = grow / 49;
    const int ag   = grow - ab * 49;
    const float* cnnb  = cnn + ((size_t)ab * GRID_N + ag) * CNN_C;
    const float* lstmb = lstm + (size_t)ab * LSTMH;

    // B staging: thread t owns full row (n0+t), 16 chunks of 8 bf16
    const int swb = t & 15;

    f32x4 acc[4][4];
    #pragma unroll
    for (int mt = 0; mt < 4; ++mt)
        #pragma unroll
        for (int nt = 0; nt < 4; ++nt)
            acc[mt][nt] = (f32x4){0.f, 0.f, 0.f, 0.f};

    float4 fa[8];      // A prefetch: 32 floats
    uint4  fb[16];     // B prefetch: 16 bf16-chunks (one row, 256B)

    auto a_load = [&](int k0) {
        const float* s = ((k0 < CNN_C) ? (cnnb + k0) : (lstmb + (k0 - CNN_C))) + seg * 32;
        #pragma unroll
        for (int i = 0; i < 8; ++i) fa[i] = ((const float4*)s)[i];
    };
    auto a_write = [&]() {
        #pragma unroll
        for (int j = 0; j < 4; ++j) {
            float f[8];
            *(float4*)&f[0] = fa[2 * j];
            *(float4*)&f[4] = fa[2 * j + 1];
            const int c = seg * 4 + j;
            *(uint4*)&Ash[ra][(c ^ swa) * 8] = pack8f(f);
        }
    };
    auto b_load = [&](int k0) {
        if constexpr (WS) {
            const unsigned short* s = wsW + (size_t)(n0 + t) * KAUG + k0;
            #pragma unroll
            for (int c = 0; c < 16; ++c) fb[c] = ((const uint4*)s)[c];
        } else {
            const float* s = (k0 < CNN_C) ? (Wc + (size_t)(n0 + t) * CNN_C + k0)
                                          : (Wl + (size_t)(n0 + t) * LSTMH + (k0 - CNN_C));
            #pragma unroll
            for (int c = 0; c < 16; ++c) {
                float f[8];
                *(float4*)&f[0] = ((const float4*)(s + c * 8))[0];
                *(float4*)&f[4] = ((const float4*)(s + c * 8))[1];
                fb[c] = pack8f(f);
            }
        }
    };
    auto b_write = [&]() {
        #pragma unroll
        for (int c = 0; c < 16; ++c)
            *(uint4*)&Bsh[t][(c ^ swb) * 8] = fb[c];
    };

    // ---- prologue: stage tile 0 ----
    a_load(0);
    b_load(0);
    a_write();
    b_write();
    __syncthreads();

    // ---- K loop: 20 tiles, 2 lgkm-only barriers per tile ----
    for (int kt = 0; kt < KTILES; ++kt) {
        const bool more = (kt + 1 < KTILES);
        if (more) {                          // issue next tile's loads before compute
            a_load((kt + 1) * BK);
            b_load((kt + 1) * BK);
        }
        // compute on resident tile
        #pragma unroll
        for (int ks = 0; ks < 4; ++ks) {
            bf16x8 af[4], bf[4];
            #pragma unroll
            for (int mt = 0; mt < 4; ++mt)
                af[mt] = *(const bf16x8*)&Ash[mt * 16 + r16][((ks * 4 + q) ^ r16) * 8];
            #pragma unroll
            for (int nt = 0; nt < 4; ++nt)
                bf[nt] = *(const bf16x8*)&Bsh[w * 64 + nt * 16 + r16][((ks * 4 + q) ^ r16) * 8];
            #pragma unroll
            for (int mt = 0; mt < 4; ++mt)
                #pragma unroll
                for (int nt = 0; nt < 4; ++nt)
                    acc[mt][nt] = __builtin_amdgcn_mfma_f32_16x16x32_bf16(
                        af[mt], bf[nt], acc[mt][nt], 0, 0, 0);
        }
        __syncthreads();                     // all reads of tile kt done
        if (more) { a_write(); b_write(); }
        __syncthreads();                     // tile kt+1 visible
    }

    // ---- epilogue: tanh + w_attn partial dot over this block's 256 cols ----
    float part[4][4];
    #pragma unroll
    for (int mt = 0; mt < 4; ++mt)
        #pragma unroll
        for (int rr = 0; rr < 4; ++rr) part[mt][rr] = 0.f;
    #pragma unroll
    for (int nt = 0; nt < 4; ++nt) {
        const int p = n0 + w * 64 + nt * 16 + r16;
        const float bb = bl[p] + bc[p];
        const float wa = wat[p];
        #pragma unroll
        for (int mt = 0; mt < 4; ++mt)
            #pragma unroll
            for (int rr = 0; rr < 4; ++rr)
                part[mt][rr] += tanh_fast(acc[mt][nt][rr] + bb) * wa;
    }
    float (*zp)[MT] = (float (*)[MT])(&Ash[0][0]);   // alias: compute reads all done
    #pragma unroll
    for (int mt = 0; mt < 4; ++mt)
        #pragma unroll
        for (int rr = 0; rr < 4; ++rr) {
            float v = part[mt][rr];
            v += __shfl_xor(v, 1);
            v += __shfl_xor(v, 2);
            v += __shfl_xor(v, 4);
            v += __shfl_xor(v, 8);           // sum over 16 cols (r16 group)
            if (r16 == 0) zp[w][mt * 16 + q * 4 + rr] = v;
        }
    __syncthreads();
    if (t < MT) {
        const float v = zp[0][t] + zp[1][t] + zp[2][t] + zp[3][t];
        const int row = m0 + t;
        const int b2  = row / 49;
        const int g2  = row - b2 * 49;
        atomicAdd(&out[g2 * BSZ + b2], v);   // scrambled position
    }
}

// Row softmax over 49 elements, in place. One wave per row.
__global__ __launch_bounds__(64) void softmax_rows(float* __restrict__ out)
{
    const int i = blockIdx.x;
    const int j = threadIdx.x;
    float x = (j < GRID_N) ? out[i * GRID_N + j] : -1e30f;
    float m = x;
    #pragma unroll
    for (int off = 32; off > 0; off >>= 1) m = fmaxf(m, __shfl_xor(m, off));
    float e = (j < GRID_N) ? __expf(x - m) : 0.f;
    float s = e;
    #pragma unroll
    for (int off = 32; off > 0; off >>= 1) s += __shfl_xor(s, off);
    if (j < GRID_N) out[i * GRID_N + j] = e / s;
}

extern "C" void kernel_launch(void* const* d_in, const int* in_sizes, int n_in,
                              void* d_out, int out_size, void* d_ws, size_t ws_size,
                              hipStream_t stream)
{
    const float* lstm = (const float*)d_in[0];
    const float* cnn  = (const float*)d_in[1];
    const float* Wl   = (const float*)d_in[2];
    const float* bl   = (const float*)d_in[3];
    const float* Wc   = (const float*)d_in[4];
    const float* bc   = (const float*)d_in[5];
    const float* wat  = (const float*)d_in[6];
    float* out = (float*)d_out;

    hipMemsetAsync(out, 0, (size_t)out_size * sizeof(float), stream);

    const size_t wneed = (size_t)PROJ * KAUG * sizeof(unsigned short);  // 2.62 MB
    if (ws_size >= wneed) {
        unsigned short* wsW = (unsigned short*)d_ws;
        prep_w<<<dim3(640), dim3(256), 0, stream>>>(Wc, Wl, wsW);
        gemm_k<true><<<dim3(NBLK), dim3(256), 0, stream>>>(lstm, cnn, Wc, Wl, bl, bc, wat, wsW, out);
    } else {
        gemm_k<false><<<dim3(NBLK), dim3(256), 0, stream>>>(lstm, cnn, Wc, Wl, bl, bc, wat, nullptr, out);
    }
    softmax_rows<<<dim3(BSZ), dim3(64), 0, stream>>>(out);
}

// Round 6
// 304.825 us; speedup vs baseline: 1.4394x; 1.4394x over previous
//
#include <hip/hip_runtime.h>
#include <math.h>

#define BSZ    256
#define GRID_N 49
#define LSTMH  512
#define CNN_C  2048
#define PROJ   512
#define KAUG   2560               // [cnn k=0..2047 | lstm k=2048..2559]
#define M_TOT  12544              // 256*49 = 392*32 exactly
#define MT     32
#define NT     256
#define BK     64
#define KTILES (KAUG / BK)        // 40
#define NBLK   ((M_TOT / MT) * (PROJ / NT))   // 392*2 = 784
#define WOFF   ((size_t)PROJ * KAUG)          // ushorts before the counter in ws

typedef short bf16x8 __attribute__((ext_vector_type(8)));
typedef float f32x4  __attribute__((ext_vector_type(4)));

static __device__ __forceinline__ unsigned short bf16_rne(float f) {
    unsigned int u = __float_as_uint(f);
    u = u + 0x7FFFu + ((u >> 16) & 1u);
    return (unsigned short)(u >> 16);
}
static __device__ __forceinline__ uint4 pack8f(const float* f) {
    uint4 o;
    o.x = (unsigned int)bf16_rne(f[0]) | ((unsigned int)bf16_rne(f[1]) << 16);
    o.y = (unsigned int)bf16_rne(f[2]) | ((unsigned int)bf16_rne(f[3]) << 16);
    o.z = (unsigned int)bf16_rne(f[4]) | ((unsigned int)bf16_rne(f[5]) << 16);
    o.w = (unsigned int)bf16_rne(f[6]) | ((unsigned int)bf16_rne(f[7]) << 16);
    return o;
}
static __device__ __forceinline__ float tanh_fast(float x) {
    float e = __expf(2.f * x);
    return 1.f - 2.f / (e + 1.f);
}
static __device__ __forceinline__ void glds16(const void* g, void* l) {
    __builtin_amdgcn_global_load_lds(
        (const __attribute__((address_space(1))) unsigned int*)g,
        (__attribute__((address_space(3))) unsigned int*)l, 16, 0, 0);
}

// ---- Prep: W_aug fp32->bf16 into ws; also zero out[] and the arrival counter ----
__global__ __launch_bounds__(256) void prep_w(const float* __restrict__ Wc,
                                              const float* __restrict__ Wl,
                                              unsigned short* __restrict__ wsW,
                                              float* __restrict__ out) {
    const int gid = blockIdx.x * 256 + threadIdx.x;   // 0..163839 = 512*320 chunks
    if (gid < M_TOT) out[gid] = 0.f;
    if (gid == 0) *(unsigned int*)(wsW + WOFF) = 0u;
    const int p  = gid / 320;
    const int kc = (gid % 320) * 8;
    const float* src = (kc < CNN_C) ? (Wc + (size_t)p * CNN_C + kc)
                                    : (Wl + (size_t)p * LSTMH + (kc - CNN_C));
    float f[8];
    *(float4*)&f[0] = ((const float4*)src)[0];
    *(float4*)&f[4] = ((const float4*)src)[1];
    *(uint4*)(wsW + (size_t)p * KAUG + kc) = pack8f(f);
}

// ---- Main GEMM: 32x256 tile, BK=64, 784 blocks (3-4/CU). r3 mechanics.
// WS path: last-arriving block does the softmax in-place (2-node graph).
template <bool WS>
__global__ __launch_bounds__(256, 4) void gemm_k(
    const float* __restrict__ lstm, const float* __restrict__ cnn,
    const float* __restrict__ Wc,   const float* __restrict__ Wl,
    const float* __restrict__ bl,   const float* __restrict__ bc,
    const float* __restrict__ wat,  unsigned short* __restrict__ wsW,
    float* __restrict__ out)
{
    __shared__ unsigned short Ash[MT][BK];   // 4 KB
    __shared__ unsigned short Bsh[NT][BK];   // 32 KB
    __shared__ unsigned int fin_old;

    const int t   = threadIdx.x;
    const int w   = t >> 6;
    const int l   = t & 63;
    const int q   = l >> 4;
    const int r16 = l & 15;

    const int m0 = (int)(blockIdx.x >> 1) * MT;
    const int n0 = (int)(blockIdx.x & 1) * NT;

    // A staging: thread t -> row ra (0..31), 8 floats at seg*8
    const int ra  = t >> 3;
    const int seg = t & 7;
    const int swa = ra & 7;
    const int grow = m0 + ra;
    const int ab   = grow / 49;
    const int ag   = grow - ab * 49;
    const float* cnnb  = cnn + ((size_t)ab * GRID_N + ag) * CNN_C;
    const float* lstmb = lstm + (size_t)ab * LSTMH;

    f32x4 acc[2][4];
    #pragma unroll
    for (int mt = 0; mt < 2; ++mt)
        #pragma unroll
        for (int nt = 0; nt < 4; ++nt)
            acc[mt][nt] = (f32x4){0.f, 0.f, 0.f, 0.f};

    float4 fa0, fa1;    // A prefetch: 8 floats

    auto a_load = [&](int k0) {
        const float* s = ((k0 < CNN_C) ? (cnnb + k0) : (lstmb + (k0 - CNN_C))) + seg * 8;
        fa0 = ((const float4*)s)[0];
        fa1 = ((const float4*)s)[1];
    };
    auto a_write = [&]() {
        float f[8];
        *(float4*)&f[0] = fa0; *(float4*)&f[4] = fa1;
        *(uint4*)&Ash[ra][(seg ^ swa) * 8] = pack8f(f);
    };
    auto b_stage = [&](int k0) {
        if constexpr (WS) {
            const int rsub = l >> 3;            // row within 8-row group
            const int cg   = (l & 7) ^ rsub;    // source chunk for store pos l&7
            #pragma unroll
            for (int j = 0; j < 8; ++j) {
                const int rowb = w * 64 + j * 8;
                const unsigned short* g =
                    wsW + (size_t)(n0 + rowb + rsub) * KAUG + k0 + cg * 8;
                glds16(g, &Bsh[rowb][0]);
            }
        } else {
            const float* s = (k0 < CNN_C) ? (Wc + (size_t)(n0 + t) * CNN_C + k0)
                                          : (Wl + (size_t)(n0 + t) * LSTMH + (k0 - CNN_C));
            const int sw = t & 7;
            #pragma unroll
            for (int c = 0; c < 8; ++c) {
                float f[8];
                *(float4*)&f[0] = ((const float4*)(s + c * 8))[0];
                *(float4*)&f[4] = ((const float4*)(s + c * 8))[1];
                *(uint4*)&Bsh[t][(c ^ sw) * 8] = pack8f(f);
            }
        }
    };

    // prologue: stage tile 0
    a_load(0);
    a_write();
    b_stage(0);
    __syncthreads();

    for (int kt = 0; kt < KTILES; ++kt) {
        const bool more = (kt + 1 < KTILES);
        if (more) a_load((kt + 1) * BK);       // latency overlapped with compute
        #pragma unroll
        for (int ks = 0; ks < 2; ++ks) {
            const int cp = ((ks * 4 + q) ^ (r16 & 7)) * 8;
            bf16x8 af[2], bfr[4];
            #pragma unroll
            for (int mt = 0; mt < 2; ++mt)
                af[mt] = *(const bf16x8*)&Ash[mt * 16 + r16][cp];
            #pragma unroll
            for (int nt = 0; nt < 4; ++nt)
                bfr[nt] = *(const bf16x8*)&Bsh[w * 64 + nt * 16 + r16][cp];
            #pragma unroll
            for (int mt = 0; mt < 2; ++mt)
                #pragma unroll
                for (int nt = 0; nt < 4; ++nt)
                    acc[mt][nt] = __builtin_amdgcn_mfma_f32_16x16x32_bf16(
                        af[mt], bfr[nt], acc[mt][nt], 0, 0, 0);
        }
        __syncthreads();                       // reads of tile kt done
        if (more) { a_write(); b_stage((kt + 1) * BK); }
        __syncthreads();                       // tile kt+1 visible
    }

    // ---- epilogue: tanh + w_attn partial dot over this block's 256 cols ----
    float part[2][4];
    #pragma unroll
    for (int mt = 0; mt < 2; ++mt)
        #pragma unroll
        for (int rr = 0; rr < 4; ++rr) part[mt][rr] = 0.f;
    #pragma unroll
    for (int nt = 0; nt < 4; ++nt) {
        const int p = n0 + w * 64 + nt * 16 + r16;
        const float bb = bl[p] + bc[p];
        const float wa = wat[p];
        #pragma unroll
        for (int mt = 0; mt < 2; ++mt)
            #pragma unroll
            for (int rr = 0; rr < 4; ++rr)
                part[mt][rr] += tanh_fast(acc[mt][nt][rr] + bb) * wa;
    }
    float (*zp)[MT] = (float (*)[MT])(&Ash[0][0]);   // alias, all LDS reads done
    #pragma unroll
    for (int mt = 0; mt < 2; ++mt)
        #pragma unroll
        for (int rr = 0; rr < 4; ++rr) {
            float v = part[mt][rr];
            v += __shfl_xor(v, 1);
            v += __shfl_xor(v, 2);
            v += __shfl_xor(v, 4);
            v += __shfl_xor(v, 8);             // sum over 16 cols (r16 group)
            if (r16 == 0) zp[w][mt * 16 + q * 4 + rr] = v;
        }
    __syncthreads();
    if (t < MT) {
        const float v = zp[0][t] + zp[1][t] + zp[2][t] + zp[3][t];
        const int row = m0 + t;
        const int b2  = row / 49;
        const int g2  = row - b2 * 49;
        atomicAdd(&out[g2 * BSZ + b2], v);     // scrambled position
    }

    if constexpr (WS) {
        // ---- last-arriving block performs the softmax (no extra kernel) ----
        __threadfence();                       // my adds visible device-wide
        __syncthreads();
        unsigned int* cnt = (unsigned int*)(wsW + WOFF);
        if (t == 0) fin_old = atomicAdd(cnt, 1u);
        __syncthreads();
        if (fin_old == NBLK - 1u) {            // deadlock-free: no waiting
            __threadfence();
            const size_t base = (size_t)t * GRID_N;   // t = row 0..255 of (256,49)
            float mx = -1e30f;
            for (int j = 0; j < GRID_N; ++j) {
                float x = __hip_atomic_load(&out[base + j], __ATOMIC_RELAXED,
                                            __HIP_MEMORY_SCOPE_AGENT);
                mx = fmaxf(mx, x);
            }
            float s = 0.f;
            for (int j = 0; j < GRID_N; ++j) {
                float x = __hip_atomic_load(&out[base + j], __ATOMIC_RELAXED,
                                            __HIP_MEMORY_SCOPE_AGENT);
                s += __expf(x - mx);
            }
            const float inv = 1.f / s;
            for (int j = 0; j < GRID_N; ++j) {
                float x = __hip_atomic_load(&out[base + j], __ATOMIC_RELAXED,
                                            __HIP_MEMORY_SCOPE_AGENT);
                out[base + j] = __expf(x - mx) * inv;
            }
        }
    }
}

// ---- fallback-only kernels (ws too small) ----
__global__ __launch_bounds__(256) void zero_out(float* __restrict__ out) {
    const int gid = blockIdx.x * 256 + threadIdx.x;
    if (gid < M_TOT) out[gid] = 0.f;
}
__global__ __launch_bounds__(64) void softmax_rows(float* __restrict__ out) {
    const int i = blockIdx.x;
    const int j = threadIdx.x;
    float x = (j < GRID_N) ? out[i * GRID_N + j] : -1e30f;
    float m = x;
    #pragma unroll
    for (int off = 32; off > 0; off >>= 1) m = fmaxf(m, __shfl_xor(m, off));
    float e = (j < GRID_N) ? __expf(x - m) : 0.f;
    float s = e;
    #pragma unroll
    for (int off = 32; off > 0; off >>= 1) s += __shfl_xor(s, off);
    if (j < GRID_N) out[i * GRID_N + j] = e / s;
}

extern "C" void kernel_launch(void* const* d_in, const int* in_sizes, int n_in,
                              void* d_out, int out_size, void* d_ws, size_t ws_size,
                              hipStream_t stream)
{
    const float* lstm = (const float*)d_in[0];
    const float* cnn  = (const float*)d_in[1];
    const float* Wl   = (const float*)d_in[2];
    const float* bl   = (const float*)d_in[3];
    const float* Wc   = (const float*)d_in[4];
    const float* bc   = (const float*)d_in[5];
    const float* wat  = (const float*)d_in[6];
    float* out = (float*)d_out;

    const size_t wneed = WOFF * sizeof(unsigned short) + sizeof(unsigned int);
    if (ws_size >= wneed) {
        unsigned short* wsW = (unsigned short*)d_ws;
        prep_w<<<dim3(640), dim3(256), 0, stream>>>(Wc, Wl, wsW, out);
        gemm_k<true><<<dim3(NBLK), dim3(256), 0, stream>>>(
            lstm, cnn, Wc, Wl, bl, bc, wat, wsW, out);
    } else {
        zero_out<<<dim3(49), dim3(256), 0, stream>>>(out);
        gemm_k<false><<<dim3(NBLK), dim3(256), 0, stream>>>(
            lstm, cnn, Wc, Wl, bl, bc, wat, nullptr, out);
        softmax_rows<<<dim3(BSZ), dim3(64), 0, stream>>>(out);
    }
}